// Round 1
// baseline (3650.488 us; speedup 1.0000x reference)
//
#include <hip/hip_runtime.h>
#include <hip/hip_bf16.h>
#include <cfloat>

#define N_TOK 8192
#define C_DIM 256
#define H_DIM 1024
#define E_ALL 32
#define E_RT  31      // routed experts (Wg cols)
#define TN    32      // tokens per tile
#define HC    128     // H chunk

// ---------------------------------------------------------------- gating ----
__global__ __launch_bounds__(64)
void gate_kernel(const float* __restrict__ x, const float* __restrict__ Wg,
                 const float* __restrict__ ebias,
                 float* __restrict__ rw,     // [N,32]
                 int* __restrict__ cnt,      // [31]
                 int* __restrict__ toks,     // [31][N]
                 float* __restrict__ wgts)   // [31][N]
{
    const int n = blockIdx.x;
    const int lane = threadIdx.x;

    __shared__ float xs[C_DIM];
    // 64 lanes * float4 = 256 floats
    ((float4*)xs)[lane] = ((const float4*)(x + (size_t)n * C_DIM))[lane];
    __syncthreads();

    float logit = -FLT_MAX;
    if (lane < E_RT) {
        float s = 0.f;
        #pragma unroll 4
        for (int c = 0; c < C_DIM; ++c)
            s = fmaf(xs[c], Wg[c * E_RT + lane], s);
        logit = s;
    }

    // softmax over lanes 0..30 (fp32, max-subtracted)
    float m = logit;
    for (int off = 32; off; off >>= 1) m = fmaxf(m, __shfl_xor(m, off));
    float ev = (lane < E_RT) ? expf(logit - m) : 0.f;
    float sum = ev;
    for (int off = 32; off; off >>= 1) sum += __shfl_xor(sum, off);
    float gate = ev / sum;
    float biased = (lane < E_RT) ? gate + ebias[lane] : -FLT_MAX;

    // top-3, lowest-index tie-break (matches lax.top_k)
    float val[3]; int idx[3];
    float cur = biased;
    #pragma unroll
    for (int k = 0; k < 3; ++k) {
        float mk = cur;
        for (int off = 32; off; off >>= 1) mk = fmaxf(mk, __shfl_xor(mk, off));
        unsigned long long ball = __ballot(cur == mk && lane < E_RT);
        int sel = __ffsll(ball) - 1;
        val[k] = mk;
        idx[k] = sel;
        if (lane == sel) cur = -FLT_MAX;
    }

    float st = val[0] + val[1] + val[2];
    float wr0 = val[0] / st * 0.75f;
    float wr1 = val[1] / st * 0.75f;
    float wr2 = val[2] / st * 0.75f;

    if (lane < E_ALL) {
        float v = 0.f;
        if (lane == 0)          v = 0.25f;
        if (lane == idx[0] + 1) v = wr0;
        if (lane == idx[1] + 1) v = wr1;
        if (lane == idx[2] + 1) v = wr2;
        rw[(size_t)n * E_ALL + lane] = v;
    }

    if (lane == 0) {
        float wv[3] = {wr0, wr1, wr2};
        #pragma unroll
        for (int k = 0; k < 3; ++k) {
            int e31 = idx[k];                       // 0..30
            int pos = atomicAdd(&cnt[e31], 1);
            toks[e31 * N_TOK + pos] = n;
            wgts[e31 * N_TOK + pos] = wv[k];
        }
    }
}

__global__ void zero_cnt(int* cnt) { if (threadIdx.x < E_RT) cnt[threadIdx.x] = 0; }

// --------------------------------------------------------------- experts ----
__global__ __launch_bounds__(256)
void expert_kernel(const float* __restrict__ x,
                   const float* __restrict__ Wfc,
                   const float* __restrict__ Wproj,
                   const int* __restrict__ cnt,
                   const int* __restrict__ toks,
                   const float* __restrict__ wgts,
                   float* __restrict__ out)
{
    const int e = blockIdx.x;
    const int count = (e == 0) ? N_TOK : cnt[e - 1];
    const int start = blockIdx.y * TN;
    if (start >= count) return;
    const int rows = min(TN, count - start);

    __shared__ float X[TN][C_DIM];   // 32 KB
    __shared__ float Hc[TN][HC];     // 16 KB
    __shared__ int   ts[TN];
    __shared__ float tw[TN];

    const int tid = threadIdx.x;
    if (tid < TN) {
        if (tid < rows) {
            if (e == 0) { ts[tid] = start + tid; tw[tid] = 0.25f; }
            else {
                ts[tid] = toks[(e - 1) * N_TOK + start + tid];
                tw[tid] = wgts[(e - 1) * N_TOK + start + tid];
            }
        } else { ts[tid] = 0; tw[tid] = 0.f; }
    }
    __syncthreads();

    // gather X rows (zero-fill tail)
    const int wave = tid >> 6, lane = tid & 63;
    for (int r = wave; r < TN; r += 4) {
        float4 v = make_float4(0.f, 0.f, 0.f, 0.f);
        if (r < rows) v = ((const float4*)(x + (size_t)ts[r] * C_DIM))[lane];
        ((float4*)X[r])[lane] = v;
    }
    __syncthreads();

    // fc mapping:   hh in {h0, h0+32, h0+64, h0+96}, rows rg*4..rg*4+3
    const int h0 = tid & 31;
    const int rg = tid >> 5;          // 0..7
    // proj mapping: cols {c0, c0+64, c0+128, c0+192}, rows rg2*8..rg2*8+7
    const int c0 = tid & 63;
    const int rg2 = tid >> 6;         // 0..3

    float acc[8][4];
    #pragma unroll
    for (int i = 0; i < 8; ++i)
        #pragma unroll
        for (int j = 0; j < 4; ++j) acc[i][j] = 0.f;

    const float* wfc = Wfc  + (size_t)e * C_DIM * H_DIM;
    const float* wpj = Wproj + (size_t)e * H_DIM * C_DIM;

    for (int hb = 0; hb < H_DIM; hb += HC) {
        // ---- fc: Hc[r][hh] = relu(x.Wfc)^2
        float s[4][4];
        #pragma unroll
        for (int j = 0; j < 4; ++j)
            #pragma unroll
            for (int i = 0; i < 4; ++i) s[j][i] = 0.f;

        for (int c = 0; c < C_DIM; c += 4) {
            float4 xv[4];
            #pragma unroll
            for (int i = 0; i < 4; ++i) xv[i] = *(const float4*)&X[rg * 4 + i][c];
            #pragma unroll
            for (int j = 0; j < 4; ++j) {
                const int col = hb + h0 + j * 32;
                const float w0 = wfc[(size_t)(c + 0) * H_DIM + col];
                const float w1 = wfc[(size_t)(c + 1) * H_DIM + col];
                const float w2 = wfc[(size_t)(c + 2) * H_DIM + col];
                const float w3 = wfc[(size_t)(c + 3) * H_DIM + col];
                #pragma unroll
                for (int i = 0; i < 4; ++i) {
                    s[j][i] = fmaf(xv[i].x, w0, s[j][i]);
                    s[j][i] = fmaf(xv[i].y, w1, s[j][i]);
                    s[j][i] = fmaf(xv[i].z, w2, s[j][i]);
                    s[j][i] = fmaf(xv[i].w, w3, s[j][i]);
                }
            }
        }
        __syncthreads();   // prior proj reads of Hc done
        #pragma unroll
        for (int j = 0; j < 4; ++j)
            #pragma unroll
            for (int i = 0; i < 4; ++i) {
                float t = fmaxf(s[j][i], 0.f);
                Hc[rg * 4 + i][h0 + j * 32] = t * t;
            }
        __syncthreads();

        // ---- proj: acc += Hc @ Wproj[chunk]
        for (int hh = 0; hh < HC; hh += 4) {
            float4 hv[8];
            #pragma unroll
            for (int i = 0; i < 8; ++i) hv[i] = *(const float4*)&Hc[rg2 * 8 + i][hh];
            #pragma unroll
            for (int q = 0; q < 4; ++q) {
                const int hrow = hb + hh + q;
                #pragma unroll
                for (int j = 0; j < 4; ++j) {
                    const float w = wpj[(size_t)hrow * C_DIM + c0 + j * 64];
                    #pragma unroll
                    for (int i = 0; i < 8; ++i) {
                        const float hval = (q == 0) ? hv[i].x : (q == 1) ? hv[i].y
                                         : (q == 2) ? hv[i].z : hv[i].w;
                        acc[i][j] = fmaf(hval, w, acc[i][j]);
                    }
                }
            }
        }
    }

    // ---- weighted scatter-add
    #pragma unroll
    for (int i = 0; i < 8; ++i) {
        const int r = rg2 * 8 + i;
        if (r < rows) {
            const float w = tw[r];
            const int base = ts[r] * C_DIM;
            #pragma unroll
            for (int j = 0; j < 4; ++j)
                atomicAdd(&out[base + c0 + j * 64], w * acc[i][j]);
        }
    }
}

// ---------------------------------------------------------------- launch ----
extern "C" void kernel_launch(void* const* d_in, const int* in_sizes, int n_in,
                              void* d_out, int out_size, void* d_ws, size_t ws_size,
                              hipStream_t stream) {
    const float* x     = (const float*)d_in[0];
    const float* Wg    = (const float*)d_in[1];
    const float* Wfc   = (const float*)d_in[2];
    const float* Wpj   = (const float*)d_in[3];
    const float* ebias = (const float*)d_in[4];

    float* out = (float*)d_out;                       // [N, C]
    float* rw  = out + (size_t)N_TOK * C_DIM;         // [N, 32]

    int*   cnt  = (int*)d_ws;
    int*   toks = cnt + 32;
    float* wgts = (float*)(toks + E_RT * N_TOK);

    hipMemsetAsync(d_out, 0, (size_t)N_TOK * C_DIM * sizeof(float), stream);
    zero_cnt<<<1, 64, 0, stream>>>(cnt);
    gate_kernel<<<N_TOK, 64, 0, stream>>>(x, Wg, ebias, rw, cnt, toks, wgts);
    expert_kernel<<<dim3(E_ALL, N_TOK / TN), 256, 0, stream>>>(x, Wfc, Wpj, cnt, toks, wgts, out);
}

// Round 2
// 2126.933 us; speedup vs baseline: 1.7163x; 1.7163x over previous
//
#include <hip/hip_runtime.h>
#include <hip/hip_bf16.h>
#include <cfloat>

#define N_TOK 8192
#define C_DIM 256
#define H_DIM 1024
#define E_ALL 32
#define E_RT  31
#define TN    64      // tokens per block (4 waves x 16 rows)
#define HC    128     // H chunk

typedef __attribute__((ext_vector_type(8))) short bf16x8;
typedef __attribute__((ext_vector_type(4))) float f32x4;

__device__ __forceinline__ unsigned short f2bf(float f) {
    return __builtin_bit_cast(unsigned short, __float2bfloat16(f));
}

// ---------------------------------------------------------------- gating ----
__global__ __launch_bounds__(64)
void gate_kernel(const float* __restrict__ x, const float* __restrict__ Wg,
                 const float* __restrict__ ebias,
                 float* __restrict__ rw, int* __restrict__ cnt,
                 int* __restrict__ toks, float* __restrict__ wgts)
{
    const int n = blockIdx.x;
    const int lane = threadIdx.x;

    __shared__ float xs[C_DIM];
    ((float4*)xs)[lane] = ((const float4*)(x + (size_t)n * C_DIM))[lane];
    __syncthreads();

    float logit = -FLT_MAX;
    if (lane < E_RT) {
        float s = 0.f;
        #pragma unroll 4
        for (int c = 0; c < C_DIM; ++c)
            s = fmaf(xs[c], Wg[c * E_RT + lane], s);
        logit = s;
    }

    float m = logit;
    for (int off = 32; off; off >>= 1) m = fmaxf(m, __shfl_xor(m, off));
    float ev = (lane < E_RT) ? expf(logit - m) : 0.f;
    float sum = ev;
    for (int off = 32; off; off >>= 1) sum += __shfl_xor(sum, off);
    float gate = ev / sum;
    float biased = (lane < E_RT) ? gate + ebias[lane] : -FLT_MAX;

    float val[3]; int idx[3];
    float cur = biased;
    #pragma unroll
    for (int k = 0; k < 3; ++k) {
        float mk = cur;
        for (int off = 32; off; off >>= 1) mk = fmaxf(mk, __shfl_xor(mk, off));
        unsigned long long ball = __ballot(cur == mk && lane < E_RT);
        int sel = __ffsll(ball) - 1;
        val[k] = mk; idx[k] = sel;
        if (lane == sel) cur = -FLT_MAX;
    }

    float st = val[0] + val[1] + val[2];
    float wr0 = val[0] / st * 0.75f;
    float wr1 = val[1] / st * 0.75f;
    float wr2 = val[2] / st * 0.75f;

    if (lane < E_ALL) {
        float v = 0.f;
        if (lane == 0)          v = 0.25f;
        if (lane == idx[0] + 1) v = wr0;
        if (lane == idx[1] + 1) v = wr1;
        if (lane == idx[2] + 1) v = wr2;
        rw[(size_t)n * E_ALL + lane] = v;
    }

    if (lane == 0) {
        float wv[3] = {wr0, wr1, wr2};
        #pragma unroll
        for (int k = 0; k < 3; ++k) {
            int e31 = idx[k];
            int pos = atomicAdd(&cnt[e31], 1);
            toks[e31 * N_TOK + pos] = n;
            wgts[e31 * N_TOK + pos] = wv[k];
        }
    }
}

__global__ void zero_cnt(int* cnt) { if (threadIdx.x < E_RT) cnt[threadIdx.x] = 0; }

// --------------------------------------------- weight transpose fp32->bf16 --
// in: [E][R][CC] fp32   out: [E][CC][R] bf16
__global__ __launch_bounds__(256)
void transpose_bf16(const float* __restrict__ in, unsigned short* __restrict__ out,
                    int R, int CC)
{
    const int e = blockIdx.z;
    const int c0 = blockIdx.x * 32, r0 = blockIdx.y * 32;
    __shared__ float t[32][33];
    const float* src = in + (size_t)e * R * CC;
    unsigned short* dst = out + (size_t)e * R * CC;
    const int tx = threadIdx.x, ty = threadIdx.y;
    #pragma unroll
    for (int i = ty; i < 32; i += 8)
        t[i][tx] = src[(size_t)(r0 + i) * CC + c0 + tx];
    __syncthreads();
    #pragma unroll
    for (int i = ty; i < 32; i += 8)
        dst[(size_t)(c0 + i) * R + r0 + tx] = f2bf(t[tx][i]);
}

// --------------------------------------------------------------- experts ----
__global__ __launch_bounds__(256)
void expert_kernel(const float* __restrict__ x,
                   const unsigned short* __restrict__ wfc_t,  // [E][H][C] bf16
                   const unsigned short* __restrict__ wpj_t,  // [E][C][H] bf16
                   const int* __restrict__ cnt,
                   const int* __restrict__ toks,
                   const float* __restrict__ wgts,
                   float* __restrict__ out)
{
    const int e = blockIdx.x;
    const int count = (e == 0) ? N_TOK : cnt[e - 1];
    const int start = blockIdx.y * TN;
    if (start >= count) return;

    __shared__ unsigned short Xs[TN * C_DIM];  // 32 KB, XOR-swizzled rows
    __shared__ unsigned short Hs[TN * HC];     // 16 KB, XOR-swizzled rows
    __shared__ int   tsL[TN];
    __shared__ float twL[TN];

    const int tid  = threadIdx.x;
    const int lane = tid & 63;
    const int w    = tid >> 6;        // wave id: owns token rows 16w..16w+15
    const int l15  = lane & 15;
    const int kg   = lane >> 4;       // 0..3

    // ---- gather my wave's 16 token rows into Xs (bf16, swizzled) ----
    for (int r = 0; r < 16; ++r) {
        const int row = w * 16 + r;
        int tok; float twv;
        if (e == 0) { tok = start + row; twv = 0.25f; }
        else {
            const int g = start + row;
            if (g < count) {
                tok = toks[(e - 1) * N_TOK + g];
                twv = wgts[(e - 1) * N_TOK + g];
            } else { tok = 0; twv = 0.f; }
        }
        if (lane == 0) { tsL[row] = tok; twL[row] = twv; }
        const float4 xv = ((const float4*)(x + (size_t)tok * C_DIM))[lane];
        ushort4 b;
        b.x = f2bf(xv.x); b.y = f2bf(xv.y); b.z = f2bf(xv.z); b.w = f2bf(xv.w);
        int byte = row * 512 + lane * 8;
        byte ^= (row & 7) << 4;
        *(ushort4*)((char*)Xs + byte) = b;
    }
    // no __syncthreads: each wave consumes only the rows it wrote

    const unsigned short* wfc = wfc_t + (size_t)e * C_DIM * H_DIM;
    const unsigned short* wpj = wpj_t + (size_t)e * C_DIM * H_DIM;

    f32x4 accP[16];
    #pragma unroll
    for (int i = 0; i < 16; ++i) accP[i] = (f32x4){0.f, 0.f, 0.f, 0.f};

    for (int hb = 0; hb < H_DIM; hb += HC) {
        // ---- fc: [16 tokens] x [C=256] @ [C][HC] -> accF (16 x 128) ----
        f32x4 accF[8];
        #pragma unroll
        for (int i = 0; i < 8; ++i) accF[i] = (f32x4){0.f, 0.f, 0.f, 0.f};

        #pragma unroll
        for (int ks = 0; ks < 8; ++ks) {                  // K over C
            const int arow = w * 16 + l15;
            int abyte = arow * 512 + (ks * 32 + kg * 8) * 2;
            abyte ^= (arow & 7) << 4;
            const bf16x8 a = *(const bf16x8*)((const char*)Xs + abyte);
            #pragma unroll
            for (int ct = 0; ct < 8; ++ct) {
                const int h = hb + ct * 16 + l15;
                const int c = ks * 32 + kg * 8;
                const bf16x8 b = *(const bf16x8*)(wfc + (size_t)h * C_DIM + c);
                accF[ct] = __builtin_amdgcn_mfma_f32_16x16x32_bf16(a, b, accF[ct], 0, 0, 0);
            }
        }

        // ---- relu^2 -> Hs bf16 (C/D layout: col=l15, row=kg*4+r) ----
        #pragma unroll
        for (int ct = 0; ct < 8; ++ct) {
            #pragma unroll
            for (int r = 0; r < 4; ++r) {
                const int row = w * 16 + kg * 4 + r;
                float t = fmaxf(accF[ct][r], 0.f);
                t *= t;
                int byte = row * 256 + (ct * 16 + l15) * 2;
                byte ^= (row & 7) << 4;
                *(unsigned short*)((char*)Hs + byte) = f2bf(t);
            }
        }
        // in-wave LDS RAW: compiler inserts lgkmcnt waits; no barrier needed

        // ---- proj: [16 tokens] x [HC] @ [HC][C=256] -> accP ----
        #pragma unroll
        for (int ks = 0; ks < 4; ++ks) {                  // K over HC
            const int arow = w * 16 + l15;
            int abyte = arow * 256 + (ks * 32 + kg * 8) * 2;
            abyte ^= (arow & 7) << 4;
            const bf16x8 a = *(const bf16x8*)((const char*)Hs + abyte);
            #pragma unroll
            for (int ct = 0; ct < 16; ++ct) {
                const int cc = ct * 16 + l15;
                const int h  = hb + ks * 32 + kg * 8;
                const bf16x8 b = *(const bf16x8*)(wpj + (size_t)cc * H_DIM + h);
                accP[ct] = __builtin_amdgcn_mfma_f32_16x16x32_bf16(a, b, accP[ct], 0, 0, 0);
            }
        }
    }

    // ---- weighted atomic scatter (C/D layout) ----
    #pragma unroll
    for (int ct = 0; ct < 16; ++ct) {
        #pragma unroll
        for (int r = 0; r < 4; ++r) {
            const int row = w * 16 + kg * 4 + r;
            const float wgt = twL[row];
            if (wgt != 0.f) {
                const int tok = tsL[row];
                atomicAdd(&out[(size_t)tok * C_DIM + ct * 16 + l15], wgt * accP[ct][r]);
            }
        }
    }
}

// ---------------------------------------------------------------- launch ----
extern "C" void kernel_launch(void* const* d_in, const int* in_sizes, int n_in,
                              void* d_out, int out_size, void* d_ws, size_t ws_size,
                              hipStream_t stream) {
    const float* x     = (const float*)d_in[0];
    const float* Wg    = (const float*)d_in[1];
    const float* Wfc   = (const float*)d_in[2];
    const float* Wpj   = (const float*)d_in[3];
    const float* ebias = (const float*)d_in[4];

    float* out = (float*)d_out;                       // [N, C]
    float* rw  = out + (size_t)N_TOK * C_DIM;         // [N, 32]

    // workspace layout (all 256B aligned)
    char* ws = (char*)d_ws;
    int*   cnt  = (int*)ws;                                        ws += 256;
    int*   toks = (int*)ws;                                        ws += (size_t)E_RT * N_TOK * 4;
    float* wgts = (float*)ws;                                      ws += (size_t)E_RT * N_TOK * 4;
    unsigned short* wfc_t = (unsigned short*)ws;                   ws += (size_t)E_ALL * C_DIM * H_DIM * 2;
    unsigned short* wpj_t = (unsigned short*)ws;

    hipMemsetAsync(d_out, 0, (size_t)N_TOK * C_DIM * sizeof(float), stream);
    zero_cnt<<<1, 64, 0, stream>>>(cnt);

    // Wfc [E][C=256][H=1024] -> wfc_t [E][H][C] bf16
    transpose_bf16<<<dim3(H_DIM / 32, C_DIM / 32, E_ALL), dim3(32, 8), 0, stream>>>(
        Wfc, wfc_t, C_DIM, H_DIM);
    // Wproj [E][H=1024][C=256] -> wpj_t [E][C][H] bf16
    transpose_bf16<<<dim3(C_DIM / 32, H_DIM / 32, E_ALL), dim3(32, 8), 0, stream>>>(
        Wpj, wpj_t, H_DIM, C_DIM);

    gate_kernel<<<N_TOK, 64, 0, stream>>>(x, Wg, ebias, rw, cnt, toks, wgts);
    expert_kernel<<<dim3(E_ALL, N_TOK / TN), 256, 0, stream>>>(
        x, wfc_t, wpj_t, cnt, toks, wgts, out);
}

// Round 3
// 950.094 us; speedup vs baseline: 3.8422x; 2.2387x over previous
//
#include <hip/hip_runtime.h>
#include <hip/hip_bf16.h>
#include <cfloat>

#define N_TOK 8192
#define C_DIM 256
#define H_DIM 1024
#define E_ALL 32
#define E_RT  31
#define TN    64                      // tokens per block (4 waves x 16)
#define HC    64                      // H chunk
#define NCHUNK (H_DIM / HC)           // 16
#define CHUNK_BYTES (HC * C_DIM * 2)  // 32768

typedef __attribute__((ext_vector_type(8))) short bf16x8;
typedef __attribute__((ext_vector_type(4))) float f32x4;

__device__ __forceinline__ unsigned short f2bf(float f) {
    return __builtin_bit_cast(unsigned short, __float2bfloat16(f));
}

__device__ __forceinline__ void gld16(void* lds, const void* g) {
    __builtin_amdgcn_global_load_lds(
        (const __attribute__((address_space(1))) void*)g,
        (__attribute__((address_space(3))) void*)lds, 16, 0, 0);
}

// ---------------------------------------------------------------- gating ----
__global__ __launch_bounds__(64)
void gate_kernel(const float* __restrict__ x, const float* __restrict__ Wg,
                 const float* __restrict__ ebias,
                 float* __restrict__ rw, int* __restrict__ cnt,
                 int* __restrict__ toks, float* __restrict__ wgts)
{
    const int n = blockIdx.x;
    const int lane = threadIdx.x;

    __shared__ float xs[C_DIM];
    ((float4*)xs)[lane] = ((const float4*)(x + (size_t)n * C_DIM))[lane];
    __syncthreads();

    float logit = -FLT_MAX;
    if (lane < E_RT) {
        float s = 0.f;
        #pragma unroll 4
        for (int c = 0; c < C_DIM; ++c)
            s = fmaf(xs[c], Wg[c * E_RT + lane], s);
        logit = s;
    }

    float m = logit;
    for (int off = 32; off; off >>= 1) m = fmaxf(m, __shfl_xor(m, off));
    float ev = (lane < E_RT) ? expf(logit - m) : 0.f;
    float sum = ev;
    for (int off = 32; off; off >>= 1) sum += __shfl_xor(sum, off);
    float gate = ev / sum;
    float biased = (lane < E_RT) ? gate + ebias[lane] : -FLT_MAX;

    float val[3]; int idx[3];
    float cur = biased;
    #pragma unroll
    for (int k = 0; k < 3; ++k) {
        float mk = cur;
        for (int off = 32; off; off >>= 1) mk = fmaxf(mk, __shfl_xor(mk, off));
        unsigned long long ball = __ballot(cur == mk && lane < E_RT);
        int sel = __ffsll(ball) - 1;
        val[k] = mk; idx[k] = sel;
        if (lane == sel) cur = -FLT_MAX;
    }

    float st = val[0] + val[1] + val[2];
    float wr0 = val[0] / st * 0.75f;
    float wr1 = val[1] / st * 0.75f;
    float wr2 = val[2] / st * 0.75f;

    if (lane < E_ALL) {
        float v = 0.f;
        if (lane == 0)          v = 0.25f;
        if (lane == idx[0] + 1) v = wr0;
        if (lane == idx[1] + 1) v = wr1;
        if (lane == idx[2] + 1) v = wr2;
        rw[(size_t)n * E_ALL + lane] = v;
    }

    if (lane == 0) {
        float wv[3] = {wr0, wr1, wr2};
        #pragma unroll
        for (int k = 0; k < 3; ++k) {
            int e31 = idx[k];
            int pos = atomicAdd(&cnt[e31], 1);
            toks[e31 * N_TOK + pos] = n;
            wgts[e31 * N_TOK + pos] = wv[k];
        }
    }
}

__global__ void zero_cnt(int* cnt) { if (threadIdx.x < E_RT) cnt[threadIdx.x] = 0; }

// ----------------------------------------------- weight prep (LDS images) ---
// Wfc [E][C][H] f32 -> img chunks [E][16][r=64][c=256] bf16, XOR-swizzled
__global__ __launch_bounds__(256)
void prep_fc(const float* __restrict__ Wfc, unsigned short* __restrict__ img)
{
    const int e = blockIdx.z;
    const int h0 = blockIdx.x * 32;
    const int c0 = blockIdx.y * 32;
    __shared__ float tb[32][33];
    const int tx = threadIdx.x, ty = threadIdx.y;
    #pragma unroll
    for (int i = ty; i < 32; i += 8)
        tb[i][tx] = Wfc[((size_t)e * C_DIM + c0 + i) * H_DIM + h0 + tx];
    __syncthreads();
    char* base = (char*)img + (size_t)e * (C_DIM * H_DIM * 2) + (h0 / HC) * CHUNK_BYTES;
    const int r0 = h0 % HC;
    #pragma unroll
    for (int i = ty; i < 32; i += 8) {
        const int r = r0 + i, c = c0 + tx;
        const int byte = (r * 512 + c * 2) ^ ((r & 7) << 4);
        *(unsigned short*)(base + byte) = f2bf(tb[tx][i]);   // Wfc[c][h0+i]
    }
}

// Wproj [E][H][C] f32 -> img chunks [E][16][cc=256][j=64] bf16, XOR-swizzled
__global__ __launch_bounds__(256)
void prep_pj(const float* __restrict__ Wpj, unsigned short* __restrict__ img)
{
    const int e = blockIdx.z;
    const int h0 = blockIdx.x * 32;
    const int c0 = blockIdx.y * 32;
    __shared__ float tb[32][33];
    const int tx = threadIdx.x, ty = threadIdx.y;
    #pragma unroll
    for (int i = ty; i < 32; i += 8)
        tb[i][tx] = Wpj[((size_t)e * H_DIM + h0 + i) * C_DIM + c0 + tx];
    __syncthreads();
    char* base = (char*)img + (size_t)e * (C_DIM * H_DIM * 2) + (h0 / HC) * CHUNK_BYTES;
    const int j0 = h0 % HC;
    #pragma unroll
    for (int i = ty; i < 32; i += 8) {
        const int cc = c0 + i, j = j0 + tx;
        const int byte = (cc * 128 + j * 2) ^ ((cc & 7) << 4);
        *(unsigned short*)(base + byte) = f2bf(tb[tx][i]);   // Wpj[h0+tx][cc]
    }
}

// --------------------------------------------------------------- experts ----
__global__ __launch_bounds__(256)
void expert_kernel(const float* __restrict__ x,
                   const unsigned short* __restrict__ wfc_img,
                   const unsigned short* __restrict__ wpj_img,
                   const int* __restrict__ cnt,
                   const int* __restrict__ toks,
                   const float* __restrict__ wgts,
                   float* __restrict__ out)
{
    const int e = blockIdx.x;
    const int count = (e == 0) ? N_TOK : cnt[e - 1];
    const int start = blockIdx.y * TN;
    if (start >= count) return;

    __shared__ unsigned short Bs[HC * C_DIM];   // 32 KB fc-weight chunk
    __shared__ unsigned short Ps[C_DIM * HC];   // 32 KB proj-weight chunk
    __shared__ unsigned short Hs[TN * HC];      // 8 KB activations
    __shared__ int   tsL[TN];
    __shared__ float twL[TN];

    const int tid  = threadIdx.x;
    const int lane = tid & 63;
    const int w    = tid >> 6;        // wave owns token rows w*16..w*16+15
    const int l15  = lane & 15;
    const int kg   = lane >> 4;       // 0..3

    // my token (keyed by l15; kg-lanes duplicate)
    const int row = w * 16 + l15;
    const int g   = start + row;
    int tok = 0; float twv = 0.f;
    if (e == 0) { tok = g; twv = 0.25f; }
    else if (g < count) {
        tok = toks[(e - 1) * N_TOK + g];
        twv = wgts[(e - 1) * N_TOK + g];
    }
    if (kg == 0) { tsL[row] = tok; twL[row] = twv; }

    // A fragments in registers for ALL chunks: token row fp32 -> bf16
    bf16x8 aF[8];
    const float* xr = x + (size_t)tok * C_DIM;
    #pragma unroll
    for (int ks = 0; ks < 8; ++ks) {
        const float4 u = *(const float4*)(xr + ks * 32 + kg * 8);
        const float4 v = *(const float4*)(xr + ks * 32 + kg * 8 + 4);
        bf16x8 a;
        a[0] = (short)f2bf(u.x); a[1] = (short)f2bf(u.y);
        a[2] = (short)f2bf(u.z); a[3] = (short)f2bf(u.w);
        a[4] = (short)f2bf(v.x); a[5] = (short)f2bf(v.y);
        a[6] = (short)f2bf(v.z); a[7] = (short)f2bf(v.w);
        aF[ks] = a;
    }

    f32x4 accP[16];
    #pragma unroll
    for (int i = 0; i < 16; ++i) accP[i] = (f32x4){0.f, 0.f, 0.f, 0.f};

    const char* gf = (const char*)wfc_img + (size_t)e * NCHUNK * CHUNK_BYTES;
    const char* gp = (const char*)wpj_img + (size_t)e * NCHUNK * CHUNK_BYTES;

    for (int t = 0; t < NCHUNK; ++t) {
        if (t) __syncthreads();                 // all waves done reading prev chunk
        #pragma unroll
        for (int i = 0; i < 8; ++i) {           // stage 64 KB: linear, pre-swizzled
            const int off = i * 4096 + tid * 16;
            gld16((char*)Bs + off, gf + (size_t)t * CHUNK_BYTES + off);
            gld16((char*)Ps + off, gp + (size_t)t * CHUNK_BYTES + off);
        }
        asm volatile("s_waitcnt vmcnt(0)" ::: "memory");
        __syncthreads();

        // ---- fc: 16 tok x 64 h, K=256
        f32x4 accF[4];
        #pragma unroll
        for (int i = 0; i < 4; ++i) accF[i] = (f32x4){0.f, 0.f, 0.f, 0.f};
        #pragma unroll
        for (int ks = 0; ks < 8; ++ks) {
            const int cb = (ks * 32 + kg * 8) * 2;
            #pragma unroll
            for (int ct = 0; ct < 4; ++ct) {
                const int r = ct * 16 + l15;
                const int byte = (r * 512 + cb) ^ ((r & 7) << 4);
                const bf16x8 b = *(const bf16x8*)((const char*)Bs + byte);
                accF[ct] = __builtin_amdgcn_mfma_f32_16x16x32_bf16(aF[ks], b, accF[ct], 0, 0, 0);
            }
        }

        // ---- relu^2 -> Hs (wave-local rows, no barrier needed)
        #pragma unroll
        for (int ct = 0; ct < 4; ++ct) {
            #pragma unroll
            for (int r = 0; r < 4; ++r) {
                const int hr = w * 16 + kg * 4 + r;
                float v = fmaxf(accF[ct][r], 0.f);
                v *= v;
                const int byte = (hr * 128 + (ct * 16 + l15) * 2) ^ ((hr & 7) << 4);
                *(unsigned short*)((char*)Hs + byte) = f2bf(v);
            }
        }

        // ---- proj: 16 tok x 256 c, K=64
        #pragma unroll
        for (int ks = 0; ks < 2; ++ks) {
            const int hb2 = (ks * 32 + kg * 8) * 2;
            const int ar = w * 16 + l15;
            const int abyte = (ar * 128 + hb2) ^ ((ar & 7) << 4);
            const bf16x8 a = *(const bf16x8*)((const char*)Hs + abyte);
            #pragma unroll
            for (int ct = 0; ct < 16; ++ct) {
                const int cc = ct * 16 + l15;
                const int byte = (cc * 128 + hb2) ^ ((cc & 7) << 4);
                const bf16x8 b = *(const bf16x8*)((const char*)Ps + byte);
                accP[ct] = __builtin_amdgcn_mfma_f32_16x16x32_bf16(a, b, accP[ct], 0, 0, 0);
            }
        }
    }

    // ---- weighted scatter (C/D layout: col=l15-block, row=kg*4+r)
    #pragma unroll
    for (int ct = 0; ct < 16; ++ct) {
        #pragma unroll
        for (int r = 0; r < 4; ++r) {
            const int m = w * 16 + kg * 4 + r;
            const float wgt = twL[m];
            if (wgt != 0.f)
                atomicAdd(&out[(size_t)tsL[m] * C_DIM + ct * 16 + l15], wgt * accP[ct][r]);
        }
    }
}

// ---------------------------------------------------------------- launch ----
extern "C" void kernel_launch(void* const* d_in, const int* in_sizes, int n_in,
                              void* d_out, int out_size, void* d_ws, size_t ws_size,
                              hipStream_t stream) {
    const float* x     = (const float*)d_in[0];
    const float* Wg    = (const float*)d_in[1];
    const float* Wfc   = (const float*)d_in[2];
    const float* Wpj   = (const float*)d_in[3];
    const float* ebias = (const float*)d_in[4];

    float* out = (float*)d_out;                       // [N, C]
    float* rw  = out + (size_t)N_TOK * C_DIM;         // [N, 32]

    char* ws = (char*)d_ws;
    int*   cnt  = (int*)ws;                                        ws += 256;
    int*   toks = (int*)ws;                                        ws += (size_t)E_RT * N_TOK * 4;
    float* wgts = (float*)ws;                                      ws += (size_t)E_RT * N_TOK * 4;
    unsigned short* wfc_img = (unsigned short*)ws;                 ws += (size_t)E_ALL * C_DIM * H_DIM * 2;
    unsigned short* wpj_img = (unsigned short*)ws;

    hipMemsetAsync(d_out, 0, (size_t)N_TOK * C_DIM * sizeof(float), stream);
    zero_cnt<<<1, 64, 0, stream>>>(cnt);

    prep_fc<<<dim3(H_DIM / 32, C_DIM / 32, E_ALL), dim3(32, 8), 0, stream>>>(Wfc, wfc_img);
    prep_pj<<<dim3(H_DIM / 32, C_DIM / 32, E_ALL), dim3(32, 8), 0, stream>>>(Wpj, wpj_img);

    gate_kernel<<<N_TOK, 64, 0, stream>>>(x, Wg, ebias, rw, cnt, toks, wgts);
    expert_kernel<<<dim3(E_ALL, N_TOK / TN), 256, 0, stream>>>(
        x, wfc_img, wpj_img, cnt, toks, wgts, out);
}

// Round 4
// 620.030 us; speedup vs baseline: 5.8876x; 1.5323x over previous
//
#include <hip/hip_runtime.h>
#include <hip/hip_bf16.h>
#include <cfloat>

#define N_TOK 8192
#define C_DIM 256
#define H_DIM 1024
#define E_ALL 32
#define E_RT  31
#define TN    64                       // tokens per block (4 waves x 16)
#define HC2   32                       // H per step
#define NST   (H_DIM / HC2)            // 32 steps
#define STEP_B (HC2 * C_DIM * 2)       // 16384 bytes per weight chunk
#define YROWS 34816                    // 8192 + 24576 + 31*64 pad, rounded

typedef __attribute__((ext_vector_type(8))) short bf16x8;
typedef __attribute__((ext_vector_type(4))) float f32x4;

__device__ __forceinline__ unsigned short f2bf(float f) {
    return __builtin_bit_cast(unsigned short, __float2bfloat16(f));
}
__device__ __forceinline__ float bf2f(unsigned short u) {
    unsigned int x = ((unsigned int)u) << 16;
    return __builtin_bit_cast(float, x);
}
__device__ __forceinline__ void gld16(void* lds, const void* g) {
    __builtin_amdgcn_global_load_lds(
        (const __attribute__((address_space(1))) void*)g,
        (__attribute__((address_space(3))) void*)lds, 16, 0, 0);
}

// ---------------------------------------------------------------- gating ----
__global__ __launch_bounds__(64)
void gate_kernel(const float* __restrict__ x, const float* __restrict__ Wg,
                 const float* __restrict__ ebias,
                 float* __restrict__ rw, int* __restrict__ cnt,
                 int* __restrict__ toks,
                 int* __restrict__ se, int* __restrict__ sp, float* __restrict__ sw)
{
    const int n = blockIdx.x;
    const int lane = threadIdx.x;

    __shared__ float xs[C_DIM];
    ((float4*)xs)[lane] = ((const float4*)(x + (size_t)n * C_DIM))[lane];
    __syncthreads();

    float logit = -FLT_MAX;
    if (lane < E_RT) {
        float s = 0.f;
        #pragma unroll 4
        for (int c = 0; c < C_DIM; ++c)
            s = fmaf(xs[c], Wg[c * E_RT + lane], s);
        logit = s;
    }

    float m = logit;
    for (int off = 32; off; off >>= 1) m = fmaxf(m, __shfl_xor(m, off));
    float ev = (lane < E_RT) ? expf(logit - m) : 0.f;
    float sum = ev;
    for (int off = 32; off; off >>= 1) sum += __shfl_xor(sum, off);
    float gate = ev / sum;
    float biased = (lane < E_RT) ? gate + ebias[lane] : -FLT_MAX;

    float val[3]; int idx[3];
    float cur = biased;
    #pragma unroll
    for (int k = 0; k < 3; ++k) {
        float mk = cur;
        for (int off = 32; off; off >>= 1) mk = fmaxf(mk, __shfl_xor(mk, off));
        unsigned long long ball = __ballot(cur == mk && lane < E_RT);
        int sel = __ffsll(ball) - 1;
        val[k] = mk; idx[k] = sel;
        if (lane == sel) cur = -FLT_MAX;
    }

    float st = val[0] + val[1] + val[2];
    float wr0 = val[0] / st * 0.75f;
    float wr1 = val[1] / st * 0.75f;
    float wr2 = val[2] / st * 0.75f;

    if (lane < E_ALL) {
        float v = 0.f;
        if (lane == 0)          v = 0.25f;
        if (lane == idx[0] + 1) v = wr0;
        if (lane == idx[1] + 1) v = wr1;
        if (lane == idx[2] + 1) v = wr2;
        rw[(size_t)n * E_ALL + lane] = v;
    }

    if (lane == 0) {
        float wv[3] = {wr0, wr1, wr2};
        #pragma unroll
        for (int k = 0; k < 3; ++k) {
            int e31 = idx[k];
            int pos = atomicAdd(&cnt[e31], 1);
            toks[e31 * N_TOK + pos] = n;
            se[n * 3 + k] = e31;
            sp[n * 3 + k] = pos;
            sw[n * 3 + k] = wv[k];
        }
    }
}

__global__ void zero_cnt(int* cnt) { if (threadIdx.x < E_RT) cnt[threadIdx.x] = 0; }

// seg[0]=0 (shared rows 0..8191); seg[e]=rowbase of routed expert e (1..31)
__global__ void finalize(const int* __restrict__ cnt, int* __restrict__ seg) {
    if (threadIdx.x == 0) {
        int b = N_TOK;
        seg[0] = 0;
        for (int i = 0; i < E_RT; ++i) { seg[i + 1] = b; b += (cnt[i] + 63) & ~63; }
    }
}

// ----------------------------------------------- weight prep (LDS images) ---
// Wfc [E][C][H] f32 -> per step s: [r=32(h)][c=256] bf16, XOR-swizzled
__global__ __launch_bounds__(256)
void prep_fc(const float* __restrict__ Wfc, unsigned short* __restrict__ img)
{
    const int e = blockIdx.z;
    const int h0 = blockIdx.x * 32;
    const int c0 = blockIdx.y * 32;
    __shared__ float tb[32][33];
    const int tx = threadIdx.x, ty = threadIdx.y;
    #pragma unroll
    for (int i = ty; i < 32; i += 8)
        tb[i][tx] = Wfc[((size_t)e * C_DIM + c0 + i) * H_DIM + h0 + tx];
    __syncthreads();
    char* base = (char*)img + (size_t)e * (C_DIM * H_DIM * 2) + (h0 / HC2) * STEP_B;
    #pragma unroll
    for (int i = ty; i < 32; i += 8) {
        const int r = i, c = c0 + tx;                       // value = Wfc[c][h0+i]
        const int byte = (r * 512 + c * 2) ^ ((r & 7) << 4);
        *(unsigned short*)(base + byte) = f2bf(tb[tx][i]);
    }
}

// Wproj [E][H][C] f32 -> per step s: [cc=256][j=32(h)] bf16, XOR-swizzled
__global__ __launch_bounds__(256)
void prep_pj(const float* __restrict__ Wpj, unsigned short* __restrict__ img)
{
    const int e = blockIdx.z;
    const int h0 = blockIdx.x * 32;
    const int c0 = blockIdx.y * 32;
    __shared__ float tb[32][33];
    const int tx = threadIdx.x, ty = threadIdx.y;
    #pragma unroll
    for (int i = ty; i < 32; i += 8)
        tb[i][tx] = Wpj[((size_t)e * H_DIM + h0 + i) * C_DIM + c0 + tx];
    __syncthreads();
    char* base = (char*)img + (size_t)e * (C_DIM * H_DIM * 2) + (h0 / HC2) * STEP_B;
    #pragma unroll
    for (int i = ty; i < 32; i += 8) {
        const int cc = c0 + i, j = tx;                      // value = Wpj[h0+tx][cc]
        const int byte = (cc * 64 + j * 2) ^ ((cc & 7) << 4);
        *(unsigned short*)(base + byte) = f2bf(tb[tx][i]);
    }
}

// --------------------------------------------------------------- experts ----
__global__ __launch_bounds__(256)
void expert_kernel(const float* __restrict__ x,
                   const unsigned short* __restrict__ wfc_img,
                   const unsigned short* __restrict__ wpj_img,
                   const int* __restrict__ cnt,
                   const int* __restrict__ seg,
                   const int* __restrict__ toks,
                   unsigned short* __restrict__ Yp)
{
    const int e = blockIdx.x;
    const int count = (e == 0) ? N_TOK : cnt[e - 1];
    const int start = blockIdx.y * TN;
    if (start >= count) return;
    const int rowbase = seg[e] + start;

    __shared__ unsigned short Bs[2][STEP_B / 2];  // 2 x 16 KB fc chunk
    __shared__ unsigned short Ps[2][STEP_B / 2];  // 2 x 16 KB proj chunk
    __shared__ unsigned short Hs[TN * HC2];       // 4 KB activations

    const int tid  = threadIdx.x;
    const int lane = tid & 63;
    const int w    = tid >> 6;
    const int l15  = lane & 15;
    const int kg   = lane >> 4;

    const int g = start + w * 16 + l15;
    int tok = 0;
    if (e == 0) tok = g;
    else if (g < count) tok = toks[(e - 1) * N_TOK + g];

    // A fragments (token row) in registers for all steps
    bf16x8 aF[8];
    const float* xr = x + (size_t)tok * C_DIM;
    #pragma unroll
    for (int ks = 0; ks < 8; ++ks) {
        const float4 u = *(const float4*)(xr + ks * 32 + kg * 8);
        const float4 v = *(const float4*)(xr + ks * 32 + kg * 8 + 4);
        bf16x8 a;
        a[0] = (short)f2bf(u.x); a[1] = (short)f2bf(u.y);
        a[2] = (short)f2bf(u.z); a[3] = (short)f2bf(u.w);
        a[4] = (short)f2bf(v.x); a[5] = (short)f2bf(v.y);
        a[6] = (short)f2bf(v.z); a[7] = (short)f2bf(v.w);
        aF[ks] = a;
    }

    f32x4 accP[16];
    #pragma unroll
    for (int i = 0; i < 16; ++i) accP[i] = (f32x4){0.f, 0.f, 0.f, 0.f};

    const char* gf = (const char*)wfc_img + (size_t)e * NST * STEP_B;
    const char* gp = (const char*)wpj_img + (size_t)e * NST * STEP_B;

    auto STAGE = [&](int buf, int s) {
        const char* srcF = gf + (size_t)s * STEP_B;
        const char* srcP = gp + (size_t)s * STEP_B;
        char* dB = (char*)Bs + buf * STEP_B;
        char* dP = (char*)Ps + buf * STEP_B;
        #pragma unroll
        for (int i = 0; i < 4; ++i) {
            const int off = i * 4096 + tid * 16;
            gld16(dB + off, srcF + off);
            gld16(dP + off, srcP + off);
        }
    };

    STAGE(0, 0);
    asm volatile("s_waitcnt vmcnt(0)" ::: "memory");
    __syncthreads();

    int buf = 0;
    for (int s = 0; s < NST; ++s) {
        if (s + 1 < NST) STAGE(buf ^ 1, s + 1);       // prefetch next chunk

        const char* bB = (const char*)Bs + buf * STEP_B;
        const char* bP = (const char*)Ps + buf * STEP_B;

        // ---- fc: 16 tok x 32 h, K=256
        f32x4 accF[2];
        accF[0] = (f32x4){0.f, 0.f, 0.f, 0.f};
        accF[1] = (f32x4){0.f, 0.f, 0.f, 0.f};
        #pragma unroll
        for (int ks = 0; ks < 8; ++ks) {
            const int cb = ks * 64 + kg * 16;
            #pragma unroll
            for (int ct = 0; ct < 2; ++ct) {
                const int r = ct * 16 + l15;
                const int byte = (r * 512 + cb) ^ ((r & 7) << 4);
                const bf16x8 b = *(const bf16x8*)(bB + byte);
                accF[ct] = __builtin_amdgcn_mfma_f32_16x16x32_bf16(aF[ks], b, accF[ct], 0, 0, 0);
            }
        }

        // ---- relu^2 -> Hs (wave-local rows)
        #pragma unroll
        for (int ct = 0; ct < 2; ++ct) {
            #pragma unroll
            for (int r = 0; r < 4; ++r) {
                const int hr = w * 16 + kg * 4 + r;
                float v = fmaxf(accF[ct][r], 0.f);
                v *= v;
                const int byte = (hr * 64 + (ct * 16 + l15) * 2) ^ ((hr & 7) << 4);
                *(unsigned short*)((char*)Hs + byte) = f2bf(v);
            }
        }

        // ---- proj: 16 tok x 256 c, K=32
        {
            const int ar = w * 16 + l15;
            const int abyte = (ar * 64 + kg * 16) ^ ((ar & 7) << 4);
            const bf16x8 a = *(const bf16x8*)((const char*)Hs + abyte);
            #pragma unroll
            for (int ct = 0; ct < 16; ++ct) {
                const int cc = ct * 16 + l15;
                const int byte = (cc * 64 + kg * 16) ^ ((cc & 7) << 4);
                const bf16x8 b = *(const bf16x8*)(bP + byte);
                accP[ct] = __builtin_amdgcn_mfma_f32_16x16x32_bf16(a, b, accP[ct], 0, 0, 0);
            }
        }

        asm volatile("s_waitcnt vmcnt(0)" ::: "memory");  // next chunk landed
        __syncthreads();                                  // all waves done with buf
        buf ^= 1;
    }

    // ---- plain (non-atomic) store of unweighted partials to own Yp rows ----
    #pragma unroll
    for (int ct = 0; ct < 16; ++ct) {
        #pragma unroll
        for (int r = 0; r < 4; ++r) {
            const int m = w * 16 + kg * 4 + r;
            Yp[(size_t)(rowbase + m) * C_DIM + ct * 16 + l15] = f2bf(accP[ct][r]);
        }
    }
}

// --------------------------------------------------------------- combine ----
__global__ __launch_bounds__(256)
void combine_kernel(const unsigned short* __restrict__ Yp,
                    const int* __restrict__ seg,
                    const int* __restrict__ se, const int* __restrict__ sp,
                    const float* __restrict__ sw,
                    float* __restrict__ out)
{
    const int t = blockIdx.x * 256 + threadIdx.x;   // 262144 threads
    const int n = t >> 5;
    const int c0 = (t & 31) * 8;

    float acc[8];
    {
        const bf16x8 y = *(const bf16x8*)(Yp + (size_t)n * C_DIM + c0);
        #pragma unroll
        for (int i = 0; i < 8; ++i) acc[i] = 0.25f * bf2f((unsigned short)y[i]);
    }
    #pragma unroll
    for (int k = 0; k < 3; ++k) {
        const int e = se[n * 3 + k];
        const int row = seg[e + 1] + sp[n * 3 + k];
        const float wgt = sw[n * 3 + k];
        const bf16x8 y = *(const bf16x8*)(Yp + (size_t)row * C_DIM + c0);
        #pragma unroll
        for (int i = 0; i < 8; ++i) acc[i] = fmaf(wgt, bf2f((unsigned short)y[i]), acc[i]);
    }
    float4 o0 = make_float4(acc[0], acc[1], acc[2], acc[3]);
    float4 o1 = make_float4(acc[4], acc[5], acc[6], acc[7]);
    *(float4*)(out + (size_t)n * C_DIM + c0)     = o0;
    *(float4*)(out + (size_t)n * C_DIM + c0 + 4) = o1;
}

// ---------------------------------------------------------------- launch ----
extern "C" void kernel_launch(void* const* d_in, const int* in_sizes, int n_in,
                              void* d_out, int out_size, void* d_ws, size_t ws_size,
                              hipStream_t stream) {
    const float* x     = (const float*)d_in[0];
    const float* Wg    = (const float*)d_in[1];
    const float* Wfc   = (const float*)d_in[2];
    const float* Wpj   = (const float*)d_in[3];
    const float* ebias = (const float*)d_in[4];

    float* out = (float*)d_out;                       // [N, C]
    float* rw  = out + (size_t)N_TOK * C_DIM;         // [N, 32]

    char* ws = (char*)d_ws;
    int*   cnt  = (int*)ws;                                        ws += 256;
    int*   seg  = (int*)ws;                                        ws += 256;
    int*   toks = (int*)ws;                                        ws += (size_t)E_RT * N_TOK * 4;
    int*   se   = (int*)ws;                                        ws += (size_t)N_TOK * 3 * 4;
    int*   sp   = (int*)ws;                                        ws += (size_t)N_TOK * 3 * 4;
    float* sw   = (float*)ws;                                      ws += (size_t)N_TOK * 3 * 4;
    unsigned short* wfc_img = (unsigned short*)ws;                 ws += (size_t)E_ALL * C_DIM * H_DIM * 2;
    unsigned short* wpj_img = (unsigned short*)ws;                 ws += (size_t)E_ALL * C_DIM * H_DIM * 2;
    unsigned short* Yp      = (unsigned short*)ws;

    zero_cnt<<<1, 64, 0, stream>>>(cnt);
    prep_fc<<<dim3(H_DIM / 32, C_DIM / 32, E_ALL), dim3(32, 8), 0, stream>>>(Wfc, wfc_img);
    prep_pj<<<dim3(H_DIM / 32, C_DIM / 32, E_ALL), dim3(32, 8), 0, stream>>>(Wpj, wpj_img);
    gate_kernel<<<N_TOK, 64, 0, stream>>>(x, Wg, ebias, rw, cnt, toks, se, sp, sw);
    finalize<<<1, 64, 0, stream>>>(cnt, seg);
    expert_kernel<<<dim3(E_ALL, N_TOK / TN), 256, 0, stream>>>(
        x, wfc_img, wpj_img, cnt, seg, toks, Yp);
    combine_kernel<<<(N_TOK * 32) / 256, 256, 0, stream>>>(Yp, seg, se, sp, sw, out);
}